// Round 6
// baseline (188.593 us; speedup 1.0000x reference)
//
#include <hip/hip_runtime.h>
#include <math.h>

#define IN_DIM 512
#define OUT_DIM 128
#define BM 64
#define BK 64
#define NKT (IN_DIM / BK)  // 8

typedef __attribute__((ext_vector_type(8))) __bf16 bf16x8;
typedef __attribute__((ext_vector_type(2))) __bf16 bf16x2;
typedef __attribute__((ext_vector_type(4))) float f32x4;
typedef __attribute__((ext_vector_type(2))) float f32x2;

// native converts -> v_cvt_pk_bf16_f32 (RNE), per m240 scalar casts beat asm
__device__ inline unsigned short f2bf(float f) {
    __bf16 h = (__bf16)f;
    return __builtin_bit_cast(unsigned short, h);
}
__device__ inline unsigned pack2f(float a, float b) {
    bf16x2 v = {(__bf16)a, (__bf16)b};
    return __builtin_bit_cast(unsigned, v);
}

// XOR-swizzled byte offset within a [rows][64-bf16] LDS tile (128 B per row).
__device__ inline int swz(int row, int kbyte) {
    return row * 128 + (kbyte ^ ((row & 7) << 4));
}

// w [512][128] f32 -> wt2 k-interleaved bf16: wt2[(k>>3)*128 + n][k&7]
__global__ void wt2_kernel(const float* __restrict__ w, unsigned short* __restrict__ wt2) {
    int idx = blockIdx.x * 256 + threadIdx.x;  // 65536 total
    int k = idx >> 7;
    int n = idx & 127;
    wt2[(((k >> 3) * 128) + n) * 8 + (k & 7)] = f2bf(w[idx]);
}

// ---------------------------------------------------------------------------
// z_bf[M,128](bf16) = x[M,512] @ w[512,128] via bf16 MFMA, fp32 accumulate.
// A converted fp32->bf16 during LDS staging (8 KB, swizzled). B fragments read
// directly from L2-resident wt2 (no LDS for B). 4 waves (2x2), wave = 32x64.
// 1-deep register prefetch on A. 6 blocks/CU.
// ---------------------------------------------------------------------------
__global__ __launch_bounds__(256, 6) void gemm_mfma(const float* __restrict__ x,
                                                    const unsigned short* __restrict__ wt2,
                                                    unsigned short* __restrict__ zb,
                                                    int M) {
    __shared__ unsigned short sA[BM * BK];  // 8 KB, swizzled
    char* const pA = (char*)sA;

    const int tid  = threadIdx.x;
    const int lane = tid & 63;
    const int wid  = tid >> 6;
    const int wm   = wid >> 1;  // 0..1
    const int wn   = wid & 1;   // 0..1
    const int block_row = blockIdx.x * BM;

    f32x4 acc[2][4];
#pragma unroll
    for (int i = 0; i < 2; ++i)
#pragma unroll
        for (int j = 0; j < 4; ++j) acc[i][j] = (f32x4){0.f, 0.f, 0.f, 0.f};

    // A staging: thread t -> row t>>2 (0..63), fp32 cols (t&3)*16 .. +16
    const int a_row = tid >> 2;
    const int a_col = (tid & 3) * 16;
    const bool a_ok = (block_row + a_row) < M;
    const float* xp = x + (size_t)(block_row + a_row) * IN_DIM + a_col;
    const int a_b0 = swz(a_row, a_col * 2);
    const int a_b1 = swz(a_row, a_col * 2 + 16);

    // MFMA fragment lane mapping
    const int fr  = lane & 15;
    const int fk4 = lane >> 4;  // k-octet group 0..3
    const int fkb = fk4 * 16;   // k byte offset in LDS row

    // B fragment base in wt2 (element units)
    const unsigned short* wtb = wt2 + (size_t)fk4 * 1024 + (wn * 64 + fr) * 8;

    float4 ra[4];
    const float4 z4 = make_float4(0.f, 0.f, 0.f, 0.f);

    // prologue: load x tile 0
#pragma unroll
    for (int i = 0; i < 4; ++i) ra[i] = a_ok ? *(const float4*)(xp + 4 * i) : z4;

#pragma unroll
    for (int kt = 0; kt < NKT; ++kt) {
        if (kt) __syncthreads();
        // fp32 -> bf16 pack (v_cvt_pk_bf16_f32) and store to LDS
        const float* rf = (const float*)ra;
        uint4 u0, u1;
        u0.x = pack2f(rf[0], rf[1]);   u0.y = pack2f(rf[2], rf[3]);
        u0.z = pack2f(rf[4], rf[5]);   u0.w = pack2f(rf[6], rf[7]);
        u1.x = pack2f(rf[8], rf[9]);   u1.y = pack2f(rf[10], rf[11]);
        u1.z = pack2f(rf[12], rf[13]); u1.w = pack2f(rf[14], rf[15]);
        *(uint4*)(pA + a_b0) = u0;
        *(uint4*)(pA + a_b1) = u1;
        __syncthreads();

        // prefetch next x tile (overlaps with MFMA below)
        if (kt + 1 < NKT) {
            const int k0 = (kt + 1) * BK;
#pragma unroll
            for (int i = 0; i < 4; ++i)
                ra[i] = a_ok ? *(const float4*)(xp + k0 + 4 * i) : z4;
        }

        // MFMA phase: A from LDS, B from L2-resident wt2
#pragma unroll
        for (int ks = 0; ks < 2; ++ks) {
            bf16x8 af[2], bv[4];
#pragma unroll
            for (int mf = 0; mf < 2; ++mf)
                af[mf] = *(const bf16x8*)(pA + swz(wm * 32 + mf * 16 + fr, ks * 64 + fkb));
#pragma unroll
            for (int nf = 0; nf < 4; ++nf)
                bv[nf] = *(const bf16x8*)(wtb + kt * 8192 + ks * 4096 + nf * 128);
#pragma unroll
            for (int mf = 0; mf < 2; ++mf)
#pragma unroll
                for (int nf = 0; nf < 4; ++nf)
                    acc[mf][nf] = __builtin_amdgcn_mfma_f32_16x16x32_bf16(
                        af[mf], bv[nf], acc[mf][nf], 0, 0, 0);
        }
    }

    // C/D layout: col = lane&15, row = (lane>>4)*4 + reg. Store bf16.
    const int crow0 = (lane >> 4) * 4;
    const int ccol  = lane & 15;
#pragma unroll
    for (int mf = 0; mf < 2; ++mf)
#pragma unroll
        for (int r = 0; r < 4; ++r) {
            const int grow = block_row + wm * 32 + mf * 16 + crow0 + r;
            if (grow < M) {
                unsigned short* zr = zb + (size_t)grow * OUT_DIM + wn * 64 + ccol;
#pragma unroll
                for (int nf = 0; nf < 4; ++nf)
                    zr[nf * 16] = f2bf(acc[mf][nf][r]);
            }
        }
}

// ---------------------------------------------------------------------------
// Decode: out[e] = sigmoid( sum_k z[a_e,k]*z[b_e,k]*w3[k] ), z in bf16.
// 16 lanes per edge, 4 edges/wave, grid-stride UNROLLED x2: both quads'
// index loads + all 4 row gathers issued before any math (2x MLP).
// ---------------------------------------------------------------------------
__device__ inline float dotw3(const uint4& ua, const uint4& ub, const f32x2* w3v) {
    const unsigned pa[4] = {ua.x, ua.y, ua.z, ua.w};
    const unsigned pb[4] = {ub.x, ub.y, ub.z, ub.w};
    f32x2 vv = (f32x2){0.f, 0.f};
#pragma unroll
    for (int i = 0; i < 4; ++i) {
        f32x2 A = (f32x2){__uint_as_float(pa[i] << 16),
                          __uint_as_float(pa[i] & 0xFFFF0000u)};
        f32x2 B = (f32x2){__uint_as_float(pb[i] << 16),
                          __uint_as_float(pb[i] & 0xFFFF0000u)};
        vv += (A * B) * w3v[i];  // v_pk_mul_f32 + v_pk_fma_f32
    }
    return vv.x + vv.y;
}

__global__ __launch_bounds__(256) void decode_kernel(const unsigned short* __restrict__ zb,
                                                     const int* __restrict__ e1,
                                                     const int* __restrict__ e2,
                                                     const float* __restrict__ w3,
                                                     float* __restrict__ out,
                                                     int E1, int E2) {
    const int tid  = threadIdx.x;
    const int lane = tid & 63;
    const int sub  = lane & 15;   // lane within 16-group
    const int sg   = lane >> 4;   // edge slot within wave (0..3)
    const int Etot = E1 + E2;
    const int nq   = (Etot + 3) >> 2;

    f32x2 w3v[4];
    {
        const float4 wlo = *(const float4*)(w3 + sub * 8);
        const float4 whi = *(const float4*)(w3 + sub * 8 + 4);
        w3v[0] = (f32x2){wlo.x, wlo.y};
        w3v[1] = (f32x2){wlo.z, wlo.w};
        w3v[2] = (f32x2){whi.x, whi.y};
        w3v[3] = (f32x2){whi.z, whi.w};
    }

    const int wave = blockIdx.x * 4 + (tid >> 6);
    const int S    = gridDim.x * 4;  // stride in quads

    for (int q = wave; q < nq; q += 2 * S) {
        const int q2   = q + S;
        const bool has2 = (q2 < nq);

        const int e_a = q * 4 + sg;
        const int e_b = has2 ? (q2 * 4 + sg) : e_a;
        const int ca  = min(e_a, Etot - 1);
        const int cb  = min(e_b, Etot - 1);

        // both index loads up front
        const int2 ia = (ca < E1) ? ((const int2*)e1)[ca] : ((const int2*)e2)[ca - E1];
        const int2 ib = (cb < E1) ? ((const int2*)e1)[cb] : ((const int2*)e2)[cb - E1];

        // all 4 row gathers issued before any math
        const uint4 a1 = *(const uint4*)(zb + (size_t)ia.x * OUT_DIM + sub * 8);
        const uint4 b1 = *(const uint4*)(zb + (size_t)ia.y * OUT_DIM + sub * 8);
        const uint4 a2 = *(const uint4*)(zb + (size_t)ib.x * OUT_DIM + sub * 8);
        const uint4 b2 = *(const uint4*)(zb + (size_t)ib.y * OUT_DIM + sub * 8);

        float v1 = dotw3(a1, b1, w3v);
        float v2 = dotw3(a2, b2, w3v);

        v1 += __shfl_xor(v1, 8);  v2 += __shfl_xor(v2, 8);
        v1 += __shfl_xor(v1, 4);  v2 += __shfl_xor(v2, 4);
        v1 += __shfl_xor(v1, 2);  v2 += __shfl_xor(v2, 2);
        v1 += __shfl_xor(v1, 1);  v2 += __shfl_xor(v2, 1);

        if (sub == 0) {
            if (e_a < Etot) out[e_a] = 1.f / (1.f + __expf(-v1));
            if (has2 && e_b < Etot) out[e_b] = 1.f / (1.f + __expf(-v2));
        }
    }
}

extern "C" void kernel_launch(void* const* d_in, const int* in_sizes, int n_in,
                              void* d_out, int out_size, void* d_ws, size_t ws_size,
                              hipStream_t stream) {
    const float* x  = (const float*)d_in[0];
    const int*   e1 = (const int*)d_in[1];
    const int*   e2 = (const int*)d_in[2];
    const float* w  = (const float*)d_in[3];
    const float* w3 = (const float*)d_in[4];

    float* out = (float*)d_out;

    const int M  = in_sizes[0] / IN_DIM;  // 100000
    const int E1 = in_sizes[1] / 2;       // 300000
    const int E2 = in_sizes[2] / 2;       // 300000

    // workspace: z_bf [M,128] bf16 (25.6 MB), then wt2 [512x128] bf16 (128 KB)
    unsigned short* zbuf = (unsigned short*)d_ws;
    unsigned short* wt2  = zbuf + (size_t)M * OUT_DIM;

    wt2_kernel<<<(IN_DIM * OUT_DIM) / 256, 256, 0, stream>>>(w, wt2);
    gemm_mfma<<<(M + BM - 1) / BM, 256, 0, stream>>>(x, wt2, zbuf, M);
    decode_kernel<<<2048, 256, 0, stream>>>(zbuf, e1, e2, w3, out, E1, E2);
}

// Round 7
// 100.960 us; speedup vs baseline: 1.8680x; 1.8680x over previous
//
#include <hip/hip_runtime.h>
#include <math.h>

#define IN_DIM 512
#define OUT_DIM 128
#define BM 64
#define BK 64
#define NKT (IN_DIM / BK)  // 8

typedef __attribute__((ext_vector_type(8))) __bf16 bf16x8;
typedef __attribute__((ext_vector_type(4))) float f32x4;
typedef __attribute__((ext_vector_type(2))) float f32x2;

// Manual RNE fp32->bf16 (bit ops). NOTE: round 6 showed that replacing these
// with native (__bf16) casts changes register allocation (VGPR 72 -> 40) and
// spills the accumulators -> 4x GEMM regression. Keep the bit-op version.
__device__ inline unsigned short f2bf(float f) {
    unsigned u = __float_as_uint(f);
    u += 0x7FFFu + ((u >> 16) & 1u);  // round-to-nearest-even
    return (unsigned short)(u >> 16);
}
__device__ inline unsigned pack2f(float a, float b) {
    return (unsigned)f2bf(a) | ((unsigned)f2bf(b) << 16);
}

// XOR-swizzled byte offset within a [rows][64-bf16] LDS tile (128 B per row).
__device__ inline int swz(int row, int kbyte) {
    return row * 128 + (kbyte ^ ((row & 7) << 4));
}

// w [512][128] f32 -> wt2 k-interleaved bf16: wt2[(k>>3)*128 + n][k&7]
__global__ void wt2_kernel(const float* __restrict__ w, unsigned short* __restrict__ wt2) {
    int idx = blockIdx.x * 256 + threadIdx.x;  // 65536 total
    int k = idx >> 7;
    int n = idx & 127;
    wt2[(((k >> 3) * 128) + n) * 8 + (k & 7)] = f2bf(w[idx]);
}

// ---------------------------------------------------------------------------
// z_bf[M,128](bf16) = x[M,512] @ w[512,128] via bf16 MFMA, fp32 accumulate.
// A converted fp32->bf16 during LDS staging (8 KB, swizzled). B fragments read
// directly from L2-resident wt2 (no LDS for B). 4 waves (2x2), wave = 32x64.
// 1-deep register prefetch on A. 6 blocks/CU.
// ---------------------------------------------------------------------------
__global__ __launch_bounds__(256, 6) void gemm_mfma(const float* __restrict__ x,
                                                    const unsigned short* __restrict__ wt2,
                                                    unsigned short* __restrict__ zb,
                                                    int M) {
    __shared__ unsigned short sA[BM * BK];  // 8 KB, swizzled
    char* const pA = (char*)sA;

    const int tid  = threadIdx.x;
    const int lane = tid & 63;
    const int wid  = tid >> 6;
    const int wm   = wid >> 1;  // 0..1
    const int wn   = wid & 1;   // 0..1
    const int block_row = blockIdx.x * BM;

    f32x4 acc[2][4];
#pragma unroll
    for (int i = 0; i < 2; ++i)
#pragma unroll
        for (int j = 0; j < 4; ++j) acc[i][j] = (f32x4){0.f, 0.f, 0.f, 0.f};

    // A staging: thread t -> row t>>2 (0..63), fp32 cols (t&3)*16 .. +16
    const int a_row = tid >> 2;
    const int a_col = (tid & 3) * 16;
    const bool a_ok = (block_row + a_row) < M;
    const float* xp = x + (size_t)(block_row + a_row) * IN_DIM + a_col;
    const int a_b0 = swz(a_row, a_col * 2);
    const int a_b1 = swz(a_row, a_col * 2 + 16);

    // MFMA fragment lane mapping
    const int fr  = lane & 15;
    const int fk4 = lane >> 4;  // k-octet group 0..3
    const int fkb = fk4 * 16;   // k byte offset in LDS row

    // B fragment base in wt2 (element units)
    const unsigned short* wtb = wt2 + (size_t)fk4 * 1024 + (wn * 64 + fr) * 8;

    float4 ra[4];
    const float4 z4 = make_float4(0.f, 0.f, 0.f, 0.f);

    // prologue: load x tile 0
#pragma unroll
    for (int i = 0; i < 4; ++i) ra[i] = a_ok ? *(const float4*)(xp + 4 * i) : z4;

#pragma unroll
    for (int kt = 0; kt < NKT; ++kt) {
        if (kt) __syncthreads();
        // fp32 -> bf16 pack and store to LDS
        const float* rf = (const float*)ra;
        uint4 u0, u1;
        u0.x = pack2f(rf[0], rf[1]);   u0.y = pack2f(rf[2], rf[3]);
        u0.z = pack2f(rf[4], rf[5]);   u0.w = pack2f(rf[6], rf[7]);
        u1.x = pack2f(rf[8], rf[9]);   u1.y = pack2f(rf[10], rf[11]);
        u1.z = pack2f(rf[12], rf[13]); u1.w = pack2f(rf[14], rf[15]);
        *(uint4*)(pA + a_b0) = u0;
        *(uint4*)(pA + a_b1) = u1;
        __syncthreads();

        // prefetch next x tile (overlaps with MFMA below)
        if (kt + 1 < NKT) {
            const int k0 = (kt + 1) * BK;
#pragma unroll
            for (int i = 0; i < 4; ++i)
                ra[i] = a_ok ? *(const float4*)(xp + k0 + 4 * i) : z4;
        }

        // MFMA phase: A from LDS, B from L2-resident wt2
#pragma unroll
        for (int ks = 0; ks < 2; ++ks) {
            bf16x8 af[2], bv[4];
#pragma unroll
            for (int mf = 0; mf < 2; ++mf)
                af[mf] = *(const bf16x8*)(pA + swz(wm * 32 + mf * 16 + fr, ks * 64 + fkb));
#pragma unroll
            for (int nf = 0; nf < 4; ++nf)
                bv[nf] = *(const bf16x8*)(wtb + kt * 8192 + ks * 4096 + nf * 128);
#pragma unroll
            for (int mf = 0; mf < 2; ++mf)
#pragma unroll
                for (int nf = 0; nf < 4; ++nf)
                    acc[mf][nf] = __builtin_amdgcn_mfma_f32_16x16x32_bf16(
                        af[mf], bv[nf], acc[mf][nf], 0, 0, 0);
        }
    }

    // C/D layout: col = lane&15, row = (lane>>4)*4 + reg. Store bf16.
    const int crow0 = (lane >> 4) * 4;
    const int ccol  = lane & 15;
#pragma unroll
    for (int mf = 0; mf < 2; ++mf)
#pragma unroll
        for (int r = 0; r < 4; ++r) {
            const int grow = block_row + wm * 32 + mf * 16 + crow0 + r;
            if (grow < M) {
                unsigned short* zr = zb + (size_t)grow * OUT_DIM + wn * 64 + ccol;
#pragma unroll
                for (int nf = 0; nf < 4; ++nf)
                    zr[nf * 16] = f2bf(acc[mf][nf][r]);
            }
        }
}

// ---------------------------------------------------------------------------
// Decode: out[e] = sigmoid( sum_k z[a_e,k]*z[b_e,k]*w3[k] ), z in bf16.
// 16 lanes per edge, 4 edges/wave, grid-stride UNROLLED x2: both quads'
// index loads + all 4 row gathers issued before any math (2x MLP).
// ---------------------------------------------------------------------------
__device__ inline float dotw3(const uint4& ua, const uint4& ub, const f32x2* w3v) {
    const unsigned pa[4] = {ua.x, ua.y, ua.z, ua.w};
    const unsigned pb[4] = {ub.x, ub.y, ub.z, ub.w};
    f32x2 vv = (f32x2){0.f, 0.f};
#pragma unroll
    for (int i = 0; i < 4; ++i) {
        f32x2 A = (f32x2){__uint_as_float(pa[i] << 16),
                          __uint_as_float(pa[i] & 0xFFFF0000u)};
        f32x2 B = (f32x2){__uint_as_float(pb[i] << 16),
                          __uint_as_float(pb[i] & 0xFFFF0000u)};
        vv += (A * B) * w3v[i];  // v_pk_mul_f32 + v_pk_fma_f32
    }
    return vv.x + vv.y;
}

__global__ __launch_bounds__(256) void decode_kernel(const unsigned short* __restrict__ zb,
                                                     const int* __restrict__ e1,
                                                     const int* __restrict__ e2,
                                                     const float* __restrict__ w3,
                                                     float* __restrict__ out,
                                                     int E1, int E2) {
    const int tid  = threadIdx.x;
    const int lane = tid & 63;
    const int sub  = lane & 15;   // lane within 16-group
    const int sg   = lane >> 4;   // edge slot within wave (0..3)
    const int Etot = E1 + E2;
    const int nq   = (Etot + 3) >> 2;

    f32x2 w3v[4];
    {
        const float4 wlo = *(const float4*)(w3 + sub * 8);
        const float4 whi = *(const float4*)(w3 + sub * 8 + 4);
        w3v[0] = (f32x2){wlo.x, wlo.y};
        w3v[1] = (f32x2){wlo.z, wlo.w};
        w3v[2] = (f32x2){whi.x, whi.y};
        w3v[3] = (f32x2){whi.z, whi.w};
    }

    const int wave = blockIdx.x * 4 + (tid >> 6);
    const int S    = gridDim.x * 4;  // stride in quads

    for (int q = wave; q < nq; q += 2 * S) {
        const int q2   = q + S;
        const bool has2 = (q2 < nq);

        const int e_a = q * 4 + sg;
        const int e_b = has2 ? (q2 * 4 + sg) : e_a;
        const int ca  = min(e_a, Etot - 1);
        const int cb  = min(e_b, Etot - 1);

        // both index loads up front
        const int2 ia = (ca < E1) ? ((const int2*)e1)[ca] : ((const int2*)e2)[ca - E1];
        const int2 ib = (cb < E1) ? ((const int2*)e1)[cb] : ((const int2*)e2)[cb - E1];

        // all 4 row gathers issued before any math
        const uint4 a1 = *(const uint4*)(zb + (size_t)ia.x * OUT_DIM + sub * 8);
        const uint4 b1 = *(const uint4*)(zb + (size_t)ia.y * OUT_DIM + sub * 8);
        const uint4 a2 = *(const uint4*)(zb + (size_t)ib.x * OUT_DIM + sub * 8);
        const uint4 b2 = *(const uint4*)(zb + (size_t)ib.y * OUT_DIM + sub * 8);

        float v1 = dotw3(a1, b1, w3v);
        float v2 = dotw3(a2, b2, w3v);

        v1 += __shfl_xor(v1, 8);  v2 += __shfl_xor(v2, 8);
        v1 += __shfl_xor(v1, 4);  v2 += __shfl_xor(v2, 4);
        v1 += __shfl_xor(v1, 2);  v2 += __shfl_xor(v2, 2);
        v1 += __shfl_xor(v1, 1);  v2 += __shfl_xor(v2, 1);

        if (sub == 0) {
            if (e_a < Etot) out[e_a] = 1.f / (1.f + __expf(-v1));
            if (has2 && e_b < Etot) out[e_b] = 1.f / (1.f + __expf(-v2));
        }
    }
}

extern "C" void kernel_launch(void* const* d_in, const int* in_sizes, int n_in,
                              void* d_out, int out_size, void* d_ws, size_t ws_size,
                              hipStream_t stream) {
    const float* x  = (const float*)d_in[0];
    const int*   e1 = (const int*)d_in[1];
    const int*   e2 = (const int*)d_in[2];
    const float* w  = (const float*)d_in[3];
    const float* w3 = (const float*)d_in[4];

    float* out = (float*)d_out;

    const int M  = in_sizes[0] / IN_DIM;  // 100000
    const int E1 = in_sizes[1] / 2;       // 300000
    const int E2 = in_sizes[2] / 2;       // 300000

    // workspace: z_bf [M,128] bf16 (25.6 MB), then wt2 [512x128] bf16 (128 KB)
    unsigned short* zbuf = (unsigned short*)d_ws;
    unsigned short* wt2  = zbuf + (size_t)M * OUT_DIM;

    wt2_kernel<<<(IN_DIM * OUT_DIM) / 256, 256, 0, stream>>>(w, wt2);
    gemm_mfma<<<(M + BM - 1) / BM, 256, 0, stream>>>(x, wt2, zbuf, M);
    decode_kernel<<<2048, 256, 0, stream>>>(zbuf, e1, e2, w3, out, E1, E2);
}